// Round 4
// baseline (1425.333 us; speedup 1.0000x reference)
//
#include <hip/hip_runtime.h>

#define VOCAB 32000
#define EMB 512
#define HID 512
#define NTAG 36
#define SEQ 512
#define G4H 2048   // 4*HID
#define NBLK 128
#define XCHUNK 32
#define MAXREP 8

typedef unsigned long long ull;

// ---------------------------------------------------------------------------
// Kernel A: Z[t][r] = W_ih[tag_t] @ emb[x_t] + b_ih[tag_t] + b_hh[tag_t]
// grid (NTAG, 32): block = (tag, 64-row chunk). 4-row batching per wave;
// W_ih read ~once. float4 x-cache fill.
// ---------------------------------------------------------------------------
__global__ __launch_bounds__(256) void precompute_z(
    const int* __restrict__ x,          // [SEQ] token ids
    const int* __restrict__ tag_ids,    // [SEQ]
    const float* __restrict__ emb,      // [VOCAB, EMB]
    const float* __restrict__ W_ih,     // [NTAG, G4H, EMB]
    const float* __restrict__ b_ih,     // [NTAG, G4H]
    const float* __restrict__ b_hh,     // [NTAG, G4H]
    float* __restrict__ Z)              // [SEQ, G4H]
{
    __shared__ int list[SEQ];
    __shared__ int cnt;
    __shared__ __align__(16) float xc[XCHUNK][EMB];   // 64 KB x-cache

    const int tid  = threadIdx.x;
    const int tag  = blockIdx.x;
    const int row0 = blockIdx.y * 64;
    const int wave = tid >> 6, lane = tid & 63;

    if (tid == 0) cnt = 0;
    __syncthreads();
    for (int t = tid; t < SEQ; t += 256)
        if (tag_ids[t] == tag) { int p = atomicAdd(&cnt, 1); list[p] = t; }
    __syncthreads();
    const int n = cnt;

    for (int c0 = 0; c0 < n; c0 += XCHUNK) {
        const int nc = min(XCHUNK, n - c0);
        __syncthreads();   // protect xc before overwrite
        for (int idx = tid; idx < nc * 128; idx += 256) {
            int tl = idx >> 7, k4 = idx & 127;
            int t = list[c0 + tl];
            ((float4*)xc[tl])[k4] = ((const float4*)(emb + (size_t)x[t] * EMB))[k4];
        }
        __syncthreads();
        for (int rr = 0; rr < 16; rr += 4) {
            const int row = row0 + wave * 16 + rr;
            const float* w0p = W_ih + ((size_t)tag * G4H + row) * EMB;
            const float* w1p = w0p + EMB;
            const float* w2p = w0p + 2 * EMB;
            const float* w3p = w0p + 3 * EMB;
            const float4 wa0 = ((const float4*)w0p)[lane], wa1 = ((const float4*)w0p)[64 + lane];
            const float4 wb0 = ((const float4*)w1p)[lane], wb1 = ((const float4*)w1p)[64 + lane];
            const float4 wc0 = ((const float4*)w2p)[lane], wc1 = ((const float4*)w2p)[64 + lane];
            const float4 wd0 = ((const float4*)w3p)[lane], wd1 = ((const float4*)w3p)[64 + lane];
            const float bi0 = b_ih[tag * G4H + row]     + b_hh[tag * G4H + row];
            const float bi1 = b_ih[tag * G4H + row + 1] + b_hh[tag * G4H + row + 1];
            const float bi2 = b_ih[tag * G4H + row + 2] + b_hh[tag * G4H + row + 2];
            const float bi3 = b_ih[tag * G4H + row + 3] + b_hh[tag * G4H + row + 3];
            for (int tl = 0; tl < nc; ++tl) {
                float4 x0 = *(const float4*)&xc[tl][4 * lane];
                float4 x1 = *(const float4*)&xc[tl][256 + 4 * lane];
                float d0 = wa0.x*x0.x + wa0.y*x0.y + wa0.z*x0.z + wa0.w*x0.w
                         + wa1.x*x1.x + wa1.y*x1.y + wa1.z*x1.z + wa1.w*x1.w;
                float d1 = wb0.x*x0.x + wb0.y*x0.y + wb0.z*x0.z + wb0.w*x0.w
                         + wb1.x*x1.x + wb1.y*x1.y + wb1.z*x1.z + wb1.w*x1.w;
                float d2 = wc0.x*x0.x + wc0.y*x0.y + wc0.z*x0.z + wc0.w*x0.w
                         + wc1.x*x1.x + wc1.y*x1.y + wc1.z*x1.z + wc1.w*x1.w;
                float d3 = wd0.x*x0.x + wd0.y*x0.y + wd0.z*x0.z + wd0.w*x0.w
                         + wd1.x*x1.x + wd1.y*x1.y + wd1.z*x1.z + wd1.w*x1.w;
                #pragma unroll
                for (int m = 32; m >= 1; m >>= 1) {
                    d0 += __shfl_xor(d0, m, 64);
                    d1 += __shfl_xor(d1, m, 64);
                    d2 += __shfl_xor(d2, m, 64);
                    d3 += __shfl_xor(d3, m, 64);
                }
                if (lane == 0) {
                    float* zr = Z + (size_t)list[c0 + tl] * G4H + row;
                    zr[0] = d0 + bi0; zr[1] = d1 + bi1;
                    zr[2] = d2 + bi2; zr[3] = d3 + bi3;
                }
            }
        }
    }
}

// ---------------------------------------------------------------------------
// Kernel B: sequential LSTM. 128 co-resident blocks; block b, wave w owns
// h index j = 4b + w. Handshake: packed {f32 h, u32 step+1} relaxed agent
// atomics into hist (R replicas). KEY R4 change: weight/Z loads are PINNED
// before the poll via asm "s_waitcnt vmcnt(0)" + memory clobber — R3's
// VGPR_Count=44 proved the compiler sank them after the poll, putting
// ~1 us of L3 weight-fetch latency on the serial critical path.
// ---------------------------------------------------------------------------
__global__ __launch_bounds__(256) void lstm_seq(
    const int* __restrict__ tag_ids,
    const float* __restrict__ h0,       // [HID]
    const float* __restrict__ c0,       // [HID]
    const float* __restrict__ W_hh,     // [NTAG, G4H, HID]
    const float* __restrict__ Z,        // [SEQ, G4H]
    const float* __restrict__ W_fc,     // [HID]
    const float* __restrict__ b_fc,     // [1]
    ull* __restrict__ hist,             // [R, SEQ, HID] packed {tag,f32} scratch
    int R,
    float* __restrict__ d_out)          // [1 + HID + HID]
{
    __shared__ int tags[SEQ];
    __shared__ __align__(16) float hsh[2][HID];
    __shared__ float red[256];

    const int tid  = threadIdx.x;
    const int b    = blockIdx.x;
    const int wave = tid >> 6, lane = tid & 63;
    const int j    = b * 4 + wave;      // owned h index
    const int crep = b % R;             // replica this block reads

    for (int t = tid; t < SEQ; t += 256) tags[t] = tag_ids[t];
    __syncthreads();

    float c    = (lane == 0) ? c0[j] : 0.f;
    float hval = 0.f;

    for (int t = 0; t < SEQ; ++t) {
        const int tag = tags[t];
        // ---- h-independent loads, issued and COMPLETED before the poll ----
        const float* wbase = W_hh + (size_t)tag * G4H * HID;
        const float4* r;
        r = (const float4*)(wbase + (size_t)(j)        * HID);
        float4 wi0 = r[lane], wi1 = r[64 + lane];
        r = (const float4*)(wbase + (size_t)(512 + j)  * HID);
        float4 wf0 = r[lane], wf1 = r[64 + lane];
        r = (const float4*)(wbase + (size_t)(1024 + j) * HID);
        float4 wg0 = r[lane], wg1 = r[64 + lane];
        r = (const float4*)(wbase + (size_t)(1536 + j) * HID);
        float4 wo0 = r[lane], wo1 = r[64 + lane];

        float zi = 0.f, zf = 0.f, zg = 0.f, zo = 0.f;
        if (lane == 0) {
            const float* zt = Z + (size_t)t * G4H;
            zi = zt[j]; zf = zt[512 + j]; zg = zt[1024 + j]; zo = zt[1536 + j];
        }

        // Pin: loads above may not sink below this point (memory clobber),
        // and are complete here (vmcnt(0)) — off the post-poll critical path.
        asm volatile("s_waitcnt vmcnt(0)" ::: "memory");

        // ---- obtain this thread's h pair (h[2tid], h[2tid+1]) ----
        float v0, v1;
        if (t == 0) {
            v0 = h0[2 * tid]; v1 = h0[2 * tid + 1];
        } else {
            const ull* hp = hist + ((size_t)crep * SEQ + (t - 1)) * HID;
            ull a  = __hip_atomic_load(&hp[2 * tid],     __ATOMIC_RELAXED, __HIP_MEMORY_SCOPE_AGENT);
            ull bq = __hip_atomic_load(&hp[2 * tid + 1], __ATOMIC_RELAXED, __HIP_MEMORY_SCOPE_AGENT);
            while ((unsigned)(a >> 32) != (unsigned)t || (unsigned)(bq >> 32) != (unsigned)t) {
                a  = __hip_atomic_load(&hp[2 * tid],     __ATOMIC_RELAXED, __HIP_MEMORY_SCOPE_AGENT);
                bq = __hip_atomic_load(&hp[2 * tid + 1], __ATOMIC_RELAXED, __HIP_MEMORY_SCOPE_AGENT);
            }
            v0 = __uint_as_float((unsigned)a);
            v1 = __uint_as_float((unsigned)bq);
        }
        const int hb = t & 1;
        hsh[hb][2 * tid]     = v0;
        hsh[hb][2 * tid + 1] = v1;
        __syncthreads();

        const float4 ha = *(const float4*)&hsh[hb][4 * lane];
        const float4 hc = *(const float4*)&hsh[hb][256 + 4 * lane];

        // ---- 4 dot products + butterfly reduce ----
        float di = wi0.x*ha.x + wi0.y*ha.y + wi0.z*ha.z + wi0.w*ha.w
                 + wi1.x*hc.x + wi1.y*hc.y + wi1.z*hc.z + wi1.w*hc.w;
        float df = wf0.x*ha.x + wf0.y*ha.y + wf0.z*ha.z + wf0.w*ha.w
                 + wf1.x*hc.x + wf1.y*hc.y + wf1.z*hc.z + wf1.w*hc.w;
        float dg = wg0.x*ha.x + wg0.y*ha.y + wg0.z*ha.z + wg0.w*ha.w
                 + wg1.x*hc.x + wg1.y*hc.y + wg1.z*hc.z + wg1.w*hc.w;
        float do_ = wo0.x*ha.x + wo0.y*ha.y + wo0.z*ha.z + wo0.w*ha.w
                  + wo1.x*hc.x + wo1.y*hc.y + wo1.z*hc.z + wo1.w*hc.w;
        #pragma unroll
        for (int m = 32; m >= 1; m >>= 1) {
            di  += __shfl_xor(di,  m, 64);
            df  += __shfl_xor(df,  m, 64);
            dg  += __shfl_xor(dg,  m, 64);
            do_ += __shfl_xor(do_, m, 64);
        }

        if (lane == 0) {
            float gi = zi + di, gf = zf + df, gg = zg + dg, go = zo + do_;
            float si = 1.f / (1.f + __expf(-gi));
            float sf = 1.f / (1.f + __expf(-gf));
            float so = 1.f / (1.f + __expf(-go));
            float tg = tanhf(gg);
            c = sf * c + si * tg;
            hval = so * tanhf(c);
            ull pk = ((ull)(unsigned)(t + 1) << 32) | (ull)__float_as_uint(hval);
            for (int rp = 0; rp < R; ++rp)
                __hip_atomic_store(&hist[((size_t)rp * SEQ + t) * HID + j], pk,
                                   __ATOMIC_RELAXED, __HIP_MEMORY_SCOPE_AGENT);
        }
        // hsh is double-buffered; the single per-step barrier bounds skew < 2.
    }

    // ---- epilogue: h, c slices ----
    if (lane == 0) {
        d_out[1 + j]       = hval;
        d_out[1 + HID + j] = c;
    }

    // ---- block 0: out = sigmoid(h_final . W_fc + b_fc) ----
    if (b == 0) {
        const ull* hp = hist + (size_t)(SEQ - 1) * HID;   // replica 0
        ull a  = __hip_atomic_load(&hp[2 * tid],     __ATOMIC_RELAXED, __HIP_MEMORY_SCOPE_AGENT);
        ull bq = __hip_atomic_load(&hp[2 * tid + 1], __ATOMIC_RELAXED, __HIP_MEMORY_SCOPE_AGENT);
        while ((unsigned)(a >> 32) != (unsigned)SEQ || (unsigned)(bq >> 32) != (unsigned)SEQ) {
            a  = __hip_atomic_load(&hp[2 * tid],     __ATOMIC_RELAXED, __HIP_MEMORY_SCOPE_AGENT);
            bq = __hip_atomic_load(&hp[2 * tid + 1], __ATOMIC_RELAXED, __HIP_MEMORY_SCOPE_AGENT);
        }
        float s = __uint_as_float((unsigned)a)  * W_fc[2 * tid]
                + __uint_as_float((unsigned)bq) * W_fc[2 * tid + 1];
        red[tid] = s;
        __syncthreads();
        #pragma unroll
        for (int off = 128; off > 0; off >>= 1) {
            if (tid < off) red[tid] += red[tid + off];
            __syncthreads();
        }
        if (tid == 0)
            d_out[0] = 1.f / (1.f + __expf(-(red[0] + b_fc[0])));
    }
}

extern "C" void kernel_launch(void* const* d_in, const int* in_sizes, int n_in,
                              void* d_out, int out_size, void* d_ws, size_t ws_size,
                              hipStream_t stream) {
    const int*   x       = (const int*)d_in[0];
    const int*   tag_ids = (const int*)d_in[1];
    const float* h0      = (const float*)d_in[2];
    const float* c0      = (const float*)d_in[3];
    const float* emb     = (const float*)d_in[4];
    const float* W_ih    = (const float*)d_in[5];
    const float* W_hh    = (const float*)d_in[6];
    const float* b_ih    = (const float*)d_in[7];
    const float* b_hh    = (const float*)d_in[8];
    const float* W_fc    = (const float*)d_in[9];
    const float* b_fc    = (const float*)d_in[10];
    float* out = (float*)d_out;

    // workspace layout: Z (4 MB) | hist replicas (R x 2 MB). No memset: 0xAA
    // poison never matches a valid step tag (1..512).
    const size_t zBytes    = (size_t)SEQ * G4H * sizeof(float);
    const size_t histBytes = (size_t)SEQ * HID * sizeof(ull);
    float* Z    = (float*)d_ws;
    ull*   hist = (ull*)((char*)d_ws + zBytes);
    int R = (int)((ws_size - zBytes) / histBytes);
    if (R > MAXREP) R = MAXREP;
    if (R < 1) R = 1;

    dim3 gA(NTAG, 32);
    precompute_z<<<gA, 256, 0, stream>>>(x, tag_ids, emb, W_ih, b_ih, b_hh, Z);
    lstm_seq<<<NBLK, 256, 0, stream>>>(tag_ids, h0, c0, W_hh, Z, W_fc, b_fc,
                                       hist, R, out);
}

// Round 5
// 1328.727 us; speedup vs baseline: 1.0727x; 1.0727x over previous
//
#include <hip/hip_runtime.h>

#define VOCAB 32000
#define EMB 512
#define HID 512
#define NTAG 36
#define SEQ 512
#define G4H 2048   // 4*HID
#define NBLK 128
#define XCHUNK 32

typedef unsigned long long ull;

__device__ __forceinline__ float fast_tanh(float x) {
    // 1 - 2/(e^{2x}+1); saturates to +-1 correctly for large |x|
    float e = __expf(2.f * x);
    return 1.f - 2.f / (e + 1.f);
}
__device__ __forceinline__ float fast_sigmoid(float x) {
    return 1.f / (1.f + __expf(-x));
}

// ---------------------------------------------------------------------------
// Kernel A: Z[t][r] = W_ih[tag_t] @ emb[x_t] + b_ih[tag_t] + b_hh[tag_t]
// grid (NTAG, 32): block = (tag, 64-row chunk). 4-row batching per wave;
// W_ih read ~once. (unchanged from R4 — will get its own round once lstm_seq
// stops dominating)
// ---------------------------------------------------------------------------
__global__ __launch_bounds__(256) void precompute_z(
    const int* __restrict__ x,          // [SEQ] token ids
    const int* __restrict__ tag_ids,    // [SEQ]
    const float* __restrict__ emb,      // [VOCAB, EMB]
    const float* __restrict__ W_ih,     // [NTAG, G4H, EMB]
    const float* __restrict__ b_ih,     // [NTAG, G4H]
    const float* __restrict__ b_hh,     // [NTAG, G4H]
    float* __restrict__ Z)              // [SEQ, G4H]
{
    __shared__ int list[SEQ];
    __shared__ int cnt;
    __shared__ __align__(16) float xc[XCHUNK][EMB];   // 64 KB x-cache

    const int tid  = threadIdx.x;
    const int tag  = blockIdx.x;
    const int row0 = blockIdx.y * 64;
    const int wave = tid >> 6, lane = tid & 63;

    if (tid == 0) cnt = 0;
    __syncthreads();
    for (int t = tid; t < SEQ; t += 256)
        if (tag_ids[t] == tag) { int p = atomicAdd(&cnt, 1); list[p] = t; }
    __syncthreads();
    const int n = cnt;

    for (int c0 = 0; c0 < n; c0 += XCHUNK) {
        const int nc = min(XCHUNK, n - c0);
        __syncthreads();   // protect xc before overwrite
        for (int idx = tid; idx < nc * 128; idx += 256) {
            int tl = idx >> 7, k4 = idx & 127;
            int t = list[c0 + tl];
            ((float4*)xc[tl])[k4] = ((const float4*)(emb + (size_t)x[t] * EMB))[k4];
        }
        __syncthreads();
        for (int rr = 0; rr < 16; rr += 4) {
            const int row = row0 + wave * 16 + rr;
            const float* w0p = W_ih + ((size_t)tag * G4H + row) * EMB;
            const float* w1p = w0p + EMB;
            const float* w2p = w0p + 2 * EMB;
            const float* w3p = w0p + 3 * EMB;
            const float4 wa0 = ((const float4*)w0p)[lane], wa1 = ((const float4*)w0p)[64 + lane];
            const float4 wb0 = ((const float4*)w1p)[lane], wb1 = ((const float4*)w1p)[64 + lane];
            const float4 wc0 = ((const float4*)w2p)[lane], wc1 = ((const float4*)w2p)[64 + lane];
            const float4 wd0 = ((const float4*)w3p)[lane], wd1 = ((const float4*)w3p)[64 + lane];
            const float bi0 = b_ih[tag * G4H + row]     + b_hh[tag * G4H + row];
            const float bi1 = b_ih[tag * G4H + row + 1] + b_hh[tag * G4H + row + 1];
            const float bi2 = b_ih[tag * G4H + row + 2] + b_hh[tag * G4H + row + 2];
            const float bi3 = b_ih[tag * G4H + row + 3] + b_hh[tag * G4H + row + 3];
            for (int tl = 0; tl < nc; ++tl) {
                float4 x0 = *(const float4*)&xc[tl][4 * lane];
                float4 x1 = *(const float4*)&xc[tl][256 + 4 * lane];
                float d0 = wa0.x*x0.x + wa0.y*x0.y + wa0.z*x0.z + wa0.w*x0.w
                         + wa1.x*x1.x + wa1.y*x1.y + wa1.z*x1.z + wa1.w*x1.w;
                float d1 = wb0.x*x0.x + wb0.y*x0.y + wb0.z*x0.z + wb0.w*x0.w
                         + wb1.x*x1.x + wb1.y*x1.y + wb1.z*x1.z + wb1.w*x1.w;
                float d2 = wc0.x*x0.x + wc0.y*x0.y + wc0.z*x0.z + wc0.w*x0.w
                         + wc1.x*x1.x + wc1.y*x1.y + wc1.z*x1.z + wc1.w*x1.w;
                float d3 = wd0.x*x0.x + wd0.y*x0.y + wd0.z*x0.z + wd0.w*x0.w
                         + wd1.x*x1.x + wd1.y*x1.y + wd1.z*x1.z + wd1.w*x1.w;
                #pragma unroll
                for (int m = 32; m >= 1; m >>= 1) {
                    d0 += __shfl_xor(d0, m, 64);
                    d1 += __shfl_xor(d1, m, 64);
                    d2 += __shfl_xor(d2, m, 64);
                    d3 += __shfl_xor(d3, m, 64);
                }
                if (lane == 0) {
                    float* zr = Z + (size_t)list[c0 + tl] * G4H + row;
                    zr[0] = d0 + bi0; zr[1] = d1 + bi1;
                    zr[2] = d2 + bi2; zr[3] = d3 + bi3;
                }
            }
        }
    }
}

// ---------------------------------------------------------------------------
// Kernel B: sequential LSTM. 128 co-resident blocks; block b, wave w owns
// h index j = 4b + w. Handshake: packed {f32 h, u32 step+1} relaxed agent
// atomics into hist. R5: depth-4 PIPELINED poll (3 samples in flight ->
// sampling period ~latency/3 instead of a full dependent load latency) +
// fast_tanh off the serial produce path + R=1 (replication proven neutral).
// No memset: 0xAA poison never matches a valid tag (1..512).
// ---------------------------------------------------------------------------
__global__ __launch_bounds__(256) void lstm_seq(
    const int* __restrict__ tag_ids,
    const float* __restrict__ h0,       // [HID]
    const float* __restrict__ c0,       // [HID]
    const float* __restrict__ W_hh,     // [NTAG, G4H, HID]
    const float* __restrict__ Z,        // [SEQ, G4H]
    const float* __restrict__ W_fc,     // [HID]
    const float* __restrict__ b_fc,     // [1]
    ull* __restrict__ hist,             // [SEQ, HID] packed {tag,f32} scratch
    float* __restrict__ d_out)          // [1 + HID + HID]
{
    __shared__ int tags[SEQ];
    __shared__ __align__(16) float hsh[2][HID];
    __shared__ float red[256];

    const int tid  = threadIdx.x;
    const int b    = blockIdx.x;
    const int wave = tid >> 6, lane = tid & 63;
    const int j    = b * 4 + wave;      // owned h index

    for (int t = tid; t < SEQ; t += 256) tags[t] = tag_ids[t];
    __syncthreads();

    float c    = (lane == 0) ? c0[j] : 0.f;
    float hval = 0.f;

    for (int t = 0; t < SEQ; ++t) {
        const int tag = tags[t];
        // ---- h-independent loads, issued and completed before the poll ----
        const float* wbase = W_hh + (size_t)tag * G4H * HID;
        const float4* r;
        r = (const float4*)(wbase + (size_t)(j)        * HID);
        float4 wi0 = r[lane], wi1 = r[64 + lane];
        r = (const float4*)(wbase + (size_t)(512 + j)  * HID);
        float4 wf0 = r[lane], wf1 = r[64 + lane];
        r = (const float4*)(wbase + (size_t)(1024 + j) * HID);
        float4 wg0 = r[lane], wg1 = r[64 + lane];
        r = (const float4*)(wbase + (size_t)(1536 + j) * HID);
        float4 wo0 = r[lane], wo1 = r[64 + lane];

        float zi = 0.f, zf = 0.f, zg = 0.f, zo = 0.f;
        if (lane == 0) {
            const float* zt = Z + (size_t)t * G4H;
            zi = zt[j]; zf = zt[512 + j]; zg = zt[1024 + j]; zo = zt[1536 + j];
        }

        // Pin: loads above may not sink below (memory clobber) and are
        // complete here — off the post-discovery critical path.
        asm volatile("s_waitcnt vmcnt(0)" ::: "memory");

        // ---- obtain this thread's h pair (h[2tid], h[2tid+1]) ----
        float v0, v1;
        if (t == 0) {
            v0 = h0[2 * tid]; v1 = h0[2 * tid + 1];
        } else {
            const ull* pa = hist + (size_t)(t - 1) * HID + 2 * tid;
            const ull* pb = pa + 1;
            const unsigned want = (unsigned)t;
            // depth-4 pipelined poll: check oldest sample while 3 newer
            // samples are already in flight -> sampling period ~ latency/3.
            ull a0 = __hip_atomic_load(pa, __ATOMIC_RELAXED, __HIP_MEMORY_SCOPE_AGENT);
            ull b0 = __hip_atomic_load(pb, __ATOMIC_RELAXED, __HIP_MEMORY_SCOPE_AGENT);
            ull a1 = __hip_atomic_load(pa, __ATOMIC_RELAXED, __HIP_MEMORY_SCOPE_AGENT);
            ull b1 = __hip_atomic_load(pb, __ATOMIC_RELAXED, __HIP_MEMORY_SCOPE_AGENT);
            ull a2 = __hip_atomic_load(pa, __ATOMIC_RELAXED, __HIP_MEMORY_SCOPE_AGENT);
            ull b2 = __hip_atomic_load(pb, __ATOMIC_RELAXED, __HIP_MEMORY_SCOPE_AGENT);
            while ((unsigned)(a0 >> 32) != want || (unsigned)(b0 >> 32) != want) {
                a0 = a1; b0 = b1;
                a1 = a2; b1 = b2;
                a2 = __hip_atomic_load(pa, __ATOMIC_RELAXED, __HIP_MEMORY_SCOPE_AGENT);
                b2 = __hip_atomic_load(pb, __ATOMIC_RELAXED, __HIP_MEMORY_SCOPE_AGENT);
            }
            v0 = __uint_as_float((unsigned)a0);
            v1 = __uint_as_float((unsigned)b0);
        }
        const int hb = t & 1;
        hsh[hb][2 * tid]     = v0;
        hsh[hb][2 * tid + 1] = v1;
        __syncthreads();

        const float4 ha = *(const float4*)&hsh[hb][4 * lane];
        const float4 hc = *(const float4*)&hsh[hb][256 + 4 * lane];

        // ---- 4 dot products + butterfly reduce ----
        float di = wi0.x*ha.x + wi0.y*ha.y + wi0.z*ha.z + wi0.w*ha.w
                 + wi1.x*hc.x + wi1.y*hc.y + wi1.z*hc.z + wi1.w*hc.w;
        float df = wf0.x*ha.x + wf0.y*ha.y + wf0.z*ha.z + wf0.w*ha.w
                 + wf1.x*hc.x + wf1.y*hc.y + wf1.z*hc.z + wf1.w*hc.w;
        float dg = wg0.x*ha.x + wg0.y*ha.y + wg0.z*ha.z + wg0.w*ha.w
                 + wg1.x*hc.x + wg1.y*hc.y + wg1.z*hc.z + wg1.w*hc.w;
        float do_ = wo0.x*ha.x + wo0.y*ha.y + wo0.z*ha.z + wo0.w*ha.w
                  + wo1.x*hc.x + wo1.y*hc.y + wo1.z*hc.z + wo1.w*hc.w;
        #pragma unroll
        for (int m = 32; m >= 1; m >>= 1) {
            di  += __shfl_xor(di,  m, 64);
            df  += __shfl_xor(df,  m, 64);
            dg  += __shfl_xor(dg,  m, 64);
            do_ += __shfl_xor(do_, m, 64);
        }

        if (lane == 0) {
            float gi = zi + di, gf = zf + df, gg = zg + dg, go = zo + do_;
            float si = fast_sigmoid(gi);
            float sf = fast_sigmoid(gf);
            float so = fast_sigmoid(go);
            float tg = fast_tanh(gg);
            c = sf * c + si * tg;
            hval = so * fast_tanh(c);
            ull pk = ((ull)(unsigned)(t + 1) << 32) | (ull)__float_as_uint(hval);
            __hip_atomic_store(&hist[(size_t)t * HID + j], pk,
                               __ATOMIC_RELAXED, __HIP_MEMORY_SCOPE_AGENT);
        }
        // hsh is double-buffered; the single per-step barrier bounds skew < 2.
    }

    // ---- epilogue: h, c slices ----
    if (lane == 0) {
        d_out[1 + j]       = hval;
        d_out[1 + HID + j] = c;
    }

    // ---- block 0: out = sigmoid(h_final . W_fc + b_fc) ----
    if (b == 0) {
        const ull* hp = hist + (size_t)(SEQ - 1) * HID;
        ull a  = __hip_atomic_load(&hp[2 * tid],     __ATOMIC_RELAXED, __HIP_MEMORY_SCOPE_AGENT);
        ull bq = __hip_atomic_load(&hp[2 * tid + 1], __ATOMIC_RELAXED, __HIP_MEMORY_SCOPE_AGENT);
        while ((unsigned)(a >> 32) != (unsigned)SEQ || (unsigned)(bq >> 32) != (unsigned)SEQ) {
            a  = __hip_atomic_load(&hp[2 * tid],     __ATOMIC_RELAXED, __HIP_MEMORY_SCOPE_AGENT);
            bq = __hip_atomic_load(&hp[2 * tid + 1], __ATOMIC_RELAXED, __HIP_MEMORY_SCOPE_AGENT);
        }
        float s = __uint_as_float((unsigned)a)  * W_fc[2 * tid]
                + __uint_as_float((unsigned)bq) * W_fc[2 * tid + 1];
        red[tid] = s;
        __syncthreads();
        #pragma unroll
        for (int off = 128; off > 0; off >>= 1) {
            if (tid < off) red[tid] += red[tid + off];
            __syncthreads();
        }
        if (tid == 0)
            d_out[0] = fast_sigmoid(red[0] + b_fc[0]);
    }
}

extern "C" void kernel_launch(void* const* d_in, const int* in_sizes, int n_in,
                              void* d_out, int out_size, void* d_ws, size_t ws_size,
                              hipStream_t stream) {
    const int*   x       = (const int*)d_in[0];
    const int*   tag_ids = (const int*)d_in[1];
    const float* h0      = (const float*)d_in[2];
    const float* c0      = (const float*)d_in[3];
    const float* emb     = (const float*)d_in[4];
    const float* W_ih    = (const float*)d_in[5];
    const float* W_hh    = (const float*)d_in[6];
    const float* b_ih    = (const float*)d_in[7];
    const float* b_hh    = (const float*)d_in[8];
    const float* W_fc    = (const float*)d_in[9];
    const float* b_fc    = (const float*)d_in[10];
    float* out = (float*)d_out;

    // workspace layout: Z (4 MB) | hist (2 MB). No memset: 0xAA poison never
    // matches a valid step tag (1..512).
    const size_t zBytes = (size_t)SEQ * G4H * sizeof(float);
    float* Z    = (float*)d_ws;
    ull*   hist = (ull*)((char*)d_ws + zBytes);

    dim3 gA(NTAG, 32);
    precompute_z<<<gA, 256, 0, stream>>>(x, tag_ids, emb, W_ih, b_ih, b_hh, Z);
    lstm_seq<<<NBLK, 256, 0, stream>>>(tag_ids, h0, c0, W_hh, Z, W_fc, b_fc,
                                       hist, out);
}